// Round 12
// baseline (117.911 us; speedup 1.0000x reference)
//
#include <hip/hip_runtime.h>
#include <math.h>

typedef short bf16x8 __attribute__((ext_vector_type(8)));
typedef _Float16 f16x8 __attribute__((ext_vector_type(8)));
typedef _Float16 f16x4 __attribute__((ext_vector_type(4)));
typedef float f32x4 __attribute__((ext_vector_type(4)));
typedef unsigned short u16x4 __attribute__((ext_vector_type(4)));
typedef unsigned short u16x8 __attribute__((ext_vector_type(8)));

#define S_LEN 2048
#define E_DIM 1024
#define H_NUM 16
#define D_DIM 64
#define LDP   (3 * E_DIM)
// softmax scale folded into Q at GEMM1 epilogue: 1/sqrt(64) * log2(e)
#define QSCALE 0.18033688011112042f

#define MFMA16(a, b, c)  __builtin_amdgcn_mfma_f32_16x16x32_bf16((a), (b), (c), 0, 0, 0)
#define MFMA16H(a, b, c) __builtin_amdgcn_mfma_f32_16x16x32_f16((a), (b), (c), 0, 0, 0)

__device__ __forceinline__ unsigned short f2bf(float f) {
    union { float f; unsigned int u; } v; v.f = f;
    unsigned int r = v.u + 0x7FFFu + ((v.u >> 16) & 1u);
    return (unsigned short)(r >> 16);
}
__device__ __forceinline__ float exp2_fast(float x) {
    float r; asm("v_exp_f32 %0, %1" : "=v"(r) : "v"(x)); return r;
}
__device__ __forceinline__ unsigned int cvt_pk_bf16(float lo, float hi) {
    unsigned int r;
    asm("v_cvt_pk_bf16_f32 %0, %1, %2" : "=v"(r) : "v"(lo), "v"(hi));
    return r;
}
// direct global -> LDS, 16B per lane. LDS dest = wave-uniform base + lane*16.
__device__ __forceinline__ void gl_lds16(const void* g, unsigned short* l) {
    __builtin_amdgcn_global_load_lds(
        (const __attribute__((address_space(1))) void*)g,
        (__attribute__((address_space(3))) void*)l, 16, 0, 0);
}

// ---------------------------------------------------------------------------
// Fused prep: [0,2048) convert qkv fp32 -> f16; [2048,2816) transpose w_in;
// [2816,3072) transpose w_out.
// ---------------------------------------------------------------------------
__global__ __launch_bounds__(256) void prep_kernel(
    const float* __restrict__ qkv, _Float16* __restrict__ Ah,
    const float* __restrict__ w_in, _Float16* __restrict__ Wt1,
    const float* __restrict__ w_out, _Float16* __restrict__ Wt2)
{
    __shared__ float tile[64][65];
    const int bid = blockIdx.x;
    const int t = threadIdx.x;

    if (bid < 2048) {
        const int i = bid * 256 + t;
        const float4 v = ((const float4*)qkv)[i];
        f16x4 hh;
        hh[0] = (_Float16)v.x; hh[1] = (_Float16)v.y;
        hh[2] = (_Float16)v.z; hh[3] = (_Float16)v.w;
        ((f16x4*)Ah)[i] = hh;
        return;
    }
    const float* B;
    _Float16* Bt;
    int bx, by, N;
    if (bid < 2816) { B = w_in;  Bt = Wt1; N = 3 * E_DIM; bx = (bid - 2048) % 48; by = (bid - 2048) / 48; }
    else            { B = w_out; Bt = Wt2; N = E_DIM;     bx = (bid - 2816) % 16; by = (bid - 2816) / 16; }
    const int K = E_DIM;
    const int k0 = by * 64, n0 = bx * 64;
    const int r4 = t >> 6, c = t & 63;
#pragma unroll
    for (int rep = 0; rep < 16; ++rep)
        tile[rep * 4 + r4][c] = B[(size_t)(k0 + rep * 4 + r4) * N + n0 + c];
    __syncthreads();
#pragma unroll
    for (int rep = 0; rep < 16; ++rep) {
        const int n = rep * 4 + r4;
        Bt[(size_t)(n0 + n) * K + k0 + c] = (_Float16)tile[c][n];
    }
}

// ---------------------------------------------------------------------------
// f16 MFMA GEMM, global_load_lds staging + LDS double buffer (r10-proven).
// ---------------------------------------------------------------------------
template <int BM, int BN, int OUT_MODE, int TWO_PASS>
__global__ __launch_bounds__(256) void gemm_f16_kernel(
    const _Float16* __restrict__ Ah, const _Float16* __restrict__ Al,
    const _Float16* __restrict__ Bt, const float* __restrict__ bias,
    void* __restrict__ Cout, int M, int N, int K, int nbx)
{
    constexpr int AROWS = TWO_PASS ? 2 * BM : BM;
    constexpr int ROWS = AROWS + BN;
    constexpr int NISS = ROWS / 16;
    constexpr int MI = BM / 32, NI = BN / 32;
    __shared__ unsigned short lds[2 * ROWS * 32];

    const int nwg = gridDim.x;
    const int bid = blockIdx.x;
    const int qch = nwg >> 3;
    const int swz = (bid & 7) * qch + (bid >> 3);
    const int n0 = (swz % nbx) * BN;
    const int m0 = (swz / nbx) * BM;

    const int t = threadIdx.x;
    const int wid = t >> 6, lane = t & 63;
    const int wr = wid >> 1, wc = wid & 1;
    const int lc = lane & 15, g = lane >> 4;
    const int lrow = lane >> 2;
    const int lcol = (lane & 3) * 8;

    f32x4 acc[MI][NI];
    const f32x4 zf = {0.f, 0.f, 0.f, 0.f};
#pragma unroll
    for (int mi = 0; mi < MI; ++mi)
#pragma unroll
        for (int ni = 0; ni < NI; ++ni) acc[mi][ni] = zf;

    auto stage = [&](int k0, int b) {
        unsigned short* base = &lds[b * ROWS * 32];
#pragma unroll
        for (int e = wid; e < NISS; e += 4) {
            const int rb = e * 16;
            const int rr = rb + lrow;
            const _Float16* gp;
            if (rb < BM)                            gp = &Ah[(size_t)(m0 + rr) * K + k0 + lcol];
            else if (TWO_PASS && rb < 2 * BM)       gp = &Al[(size_t)(m0 + rr - BM) * K + k0 + lcol];
            else                                    gp = &Bt[(size_t)(n0 + rr - AROWS) * K + k0 + lcol];
            gl_lds16(gp, base + rb * 32);
        }
    };

    stage(0, 0);
    const int NK = K / 32;
    for (int ks = 0; ks < NK; ++ks) {
        __syncthreads();
        if (ks + 1 < NK) stage((ks + 1) * 32, (ks + 1) & 1);
        const unsigned short* cb = &lds[(ks & 1) * ROWS * 32];

        f16x8 bfr[NI];
#pragma unroll
        for (int ni = 0; ni < NI; ++ni)
            bfr[ni] = *(const f16x8*)&cb[(AROWS + wc * (BN / 2) + ni * 16 + lc) * 32 + g * 8];
#pragma unroll
        for (int mi = 0; mi < MI; ++mi) {
            const int ar = wr * (BM / 2) + mi * 16 + lc;
            const f16x8 ah = *(const f16x8*)&cb[ar * 32 + g * 8];
#pragma unroll
            for (int ni = 0; ni < NI; ++ni)
                acc[mi][ni] = MFMA16H(ah, bfr[ni], acc[mi][ni]);
            if (TWO_PASS) {
                const f16x8 al = *(const f16x8*)&cb[(BM + ar) * 32 + g * 8];
#pragma unroll
                for (int ni = 0; ni < NI; ++ni)
                    acc[mi][ni] = MFMA16H(al, bfr[ni], acc[mi][ni]);
            }
        }
    }

#pragma unroll
    for (int ni = 0; ni < NI; ++ni) {
        const int col = n0 + wc * (BN / 2) + ni * 16 + lc;
        const float bv = bias[col];
        float sc = 1.f;
        if (OUT_MODE == 1) sc = (col < E_DIM) ? QSCALE : 1.f;
#pragma unroll
        for (int mi = 0; mi < MI; ++mi) {
            const int rbase = m0 + wr * (BM / 2) + mi * 16 + g * 4;
#pragma unroll
            for (int i = 0; i < 4; ++i) {
                const float v = acc[mi][ni][i] + bv;
                if (OUT_MODE == 1)
                    ((unsigned short*)Cout)[(size_t)(rbase + i) * N + col] = f2bf(v * sc);
                else
                    ((float*)Cout)[(size_t)(rbase + i) * N + col] = v;
            }
        }
    }
}

// ---------------------------------------------------------------------------
// MFMA flash attention, 2-subtile waves (32 q-rows each) to halve LDS reads
// per q. Block = 64 Q rows x head, 8 waves (512 thr): qg=w&1 (32 q-rows),
// quarter qq=w>>1 (512 kv, 8 tiles of KVB=64). K staged via global_load_lds
// with pre-swizzled SOURCE (LDS linear, m173); V reg-transposed (T14
// prefetch); Q frags hoisted from global once. V-frag reads shared across
// both subtiles (P chunks for both subtiles coexist). 4-way in-LDS merge.
// LDS = K 32KB | V 32KB | P 16KB = 80KB -> 2 blocks/CU.
// ---------------------------------------------------------------------------
__global__ __launch_bounds__(512, 4) void attn_mfma_kernel(
    const unsigned short* __restrict__ proj, _Float16* __restrict__ Oh)
{
    __shared__ unsigned short lds[40960];   // 80 KB
    float* ldsf = (float*)lds;              // merge scratch overlays dead K/V

    const int t = threadIdx.x;
    const int w = t >> 6, lane = t & 63;
    const int lc = lane & 15, g = lane >> 4;
    const int qg = w & 1;        // q-row group (32 rows)
    const int qq = w >> 1;       // kv quarter
    const int ts = t & 127;      // 128-thread quarter staging group

    const int bid = blockIdx.x;
    const int swb = (bid & 7) * 64 + (bid >> 3);
    const int qt = swb & 31;
    const int h  = swb >> 5;
    const int q0 = qt * 64;

    const size_t qoff = (size_t)h * D_DIM;
    const size_t koff = E_DIM + (size_t)h * D_DIM;
    const size_t voff = 2 * E_DIM + (size_t)h * D_DIM;

    const int KO = qq * 4096;            // K quarter base (elems)
    const int VO = 16384 + qq * 4096;    // Vt quarter base
    const int kvbase = qq * 512;

    // --- V staging coords (128-thread quarter group; reg-transpose) ---
    const int kvv = (ts & 15) * 4;       // V src kv rows (4)
    const int vd0 = (ts >> 4) * 8;       // V dst d rows (8)
    u16x8 vr[4];
    auto load_v = [&](int tile) {
        const int t0 = kvbase + tile * 64;
#pragma unroll
        for (int j = 0; j < 4; ++j)
            vr[j] = *(const u16x8*)&proj[(size_t)(t0 + kvv + j) * LDP + voff + vd0];
    };
    auto store_v = [&]() {
#pragma unroll
        for (int dd = 0; dd < 8; ++dd) {
            const int d = vd0 + dd;
            u16x4 w4;
            w4[0] = vr[0][dd]; w4[1] = vr[1][dd]; w4[2] = vr[2][dd]; w4[3] = vr[3][dd];
            *(u16x4*)&lds[VO + d * 64 + (kvv ^ ((d & 7) << 3))] = w4;
        }
    };

    // --- K staging: global_load_lds, pre-swizzled source, linear LDS dest ---
    const int klr = lane >> 3;           // 0..7 row within 8-row issue
    const int ksl = lane & 7;            // dest slot
    const int ksrc = (ksl ^ klr) * 8;    // pre-swizzled source column (elems)
    auto stage_k = [&](int tile) {
        const int t0 = kvbase + tile * 64;
        const int e0 = (w & 1) * 4;      // each of the quarter's 2 waves does 32 rows
#pragma unroll
        for (int e = 0; e < 4; ++e) {
            const int rb = (e0 + e) * 8;
            gl_lds16(&proj[(size_t)(t0 + rb + klr) * LDP + koff + ksrc],
                     &lds[KO + rb * 64]);
        }
    };

    // --- prologue: stage tile 0 (V via regs, K via gl_lds) ---
    load_v(0);
    store_v();
    stage_k(0);

    // hoist Q fragments straight from global (once; L2-hot): 2 subtiles
    bf16x8 qB0[2], qB1[2];
#pragma unroll
    for (int s = 0; s < 2; ++s) {
        const size_t rq = (size_t)(q0 + qg * 32 + s * 16 + lc) * LDP + qoff;
        qB0[s] = *(const bf16x8*)&proj[rq + g * 8];
        qB1[s] = *(const bf16x8*)&proj[rq + 32 + g * 8];
    }
    __syncthreads();   // drains gl_lds (vmcnt) + ds writes

    f32x4 oacc[2][4];
    const f32x4 zf = {0.f, 0.f, 0.f, 0.f};
#pragma unroll
    for (int s = 0; s < 2; ++s)
#pragma unroll
        for (int i = 0; i < 4; ++i) oacc[s][i] = zf;
    float mrun[2] = {-1e30f, -1e30f};
    float lsum[2] = {0.f, 0.f};

    // per-(wave,subtile) P chunk: 16 rows x 32 kv, both subtiles live
    const int pb0 = 32768 + (w * 2 + 0) * 512 + lc * 32;
    const int pb1 = 32768 + (w * 2 + 1) * 512 + lc * 32;
    const int psw = ((lc >> 1) & 3) << 3;

    const int NTH = 512 / 64;   // 8 tiles per quarter
    for (int tt = 0; tt < NTH; ++tt) {
        if (tt + 1 < NTH) load_v(tt + 1);   // T14: issue early

        // --- QK^T (swapped: A=K, B=Q), 2 subtiles share every K-frag ---
        f32x4 sacc[2][4];
#pragma unroll
        for (int s = 0; s < 2; ++s)
#pragma unroll
            for (int c = 0; c < 4; ++c) sacc[s][c] = zf;
        __builtin_amdgcn_s_setprio(1);
#pragma unroll
        for (int c = 0; c < 4; ++c) {
            const int kr = c * 16 + lc;
            const int swk = (kr & 7) << 3;
            const bf16x8 kf0 = *(const bf16x8*)&lds[KO + kr * 64 + ((g * 8) ^ swk)];
            const bf16x8 kf1 = *(const bf16x8*)&lds[KO + kr * 64 + ((32 + g * 8) ^ swk)];
            sacc[0][c] = MFMA16(kf0, qB0[0], sacc[0][c]);
            sacc[0][c] = MFMA16(kf1, qB1[0], sacc[0][c]);
            sacc[1][c] = MFMA16(kf0, qB0[1], sacc[1][c]);
            sacc[1][c] = MFMA16(kf1, qB1[1], sacc[1][c]);
        }
        __builtin_amdgcn_s_setprio(0);

        // --- defer-max (T13): no cross-lane data in common path ---
        float lmax[2];
#pragma unroll
        for (int s = 0; s < 2; ++s) {
            float m01 = fmaxf(fmaxf(sacc[s][0][0], sacc[s][0][1]), fmaxf(sacc[s][0][2], sacc[s][0][3]));
            m01 = fmaxf(m01, fmaxf(fmaxf(sacc[s][1][0], sacc[s][1][1]), fmaxf(sacc[s][1][2], sacc[s][1][3])));
            m01 = fmaxf(m01, fmaxf(fmaxf(sacc[s][2][0], sacc[s][2][1]), fmaxf(sacc[s][2][2], sacc[s][2][3])));
            m01 = fmaxf(m01, fmaxf(fmaxf(sacc[s][3][0], sacc[s][3][1]), fmaxf(sacc[s][3][2], sacc[s][3][3])));
            lmax[s] = m01;
        }
        if (__any(fmaxf(lmax[0] - mrun[0], lmax[1] - mrun[1]) > 8.0f)) {
#pragma unroll
            for (int s = 0; s < 2; ++s) {
                float mx = lmax[s];
                mx = fmaxf(mx, __shfl_xor(mx, 16));
                mx = fmaxf(mx, __shfl_xor(mx, 32));
                const float mnew = fmaxf(mrun[s], mx);
                const float fs = exp2_fast(mrun[s] - mnew);
                lsum[s] *= fs;
                mrun[s] = mnew;
#pragma unroll
                for (int i = 0; i < 4; ++i) {
                    const float fsi = __shfl(fs, 4 * g + i, 16);
                    oacc[s][0][i] *= fsi; oacc[s][1][i] *= fsi;
                    oacc[s][2][i] *= fsi; oacc[s][3][i] *= fsi;
                }
            }
        }

        // --- exp (base-2, stale max: P <= 2^8) + per-lane partial sums ---
#pragma unroll
        for (int s = 0; s < 2; ++s) {
#pragma unroll
            for (int c = 0; c < 4; ++c)
#pragma unroll
                for (int i = 0; i < 4; ++i)
                    sacc[s][c][i] = exp2_fast(sacc[s][c][i] - mrun[s]);
            lsum[s] += ((sacc[s][0][0] + sacc[s][0][1]) + (sacc[s][0][2] + sacc[s][0][3]))
                     + ((sacc[s][1][0] + sacc[s][1][1]) + (sacc[s][1][2] + sacc[s][1][3]))
                     + ((sacc[s][2][0] + sacc[s][2][1]) + (sacc[s][2][2] + sacc[s][2][3]))
                     + ((sacc[s][3][0] + sacc[s][3][1]) + (sacc[s][3][2] + sacc[s][3][3]));
        }

        // --- PV: per kv-half, both subtiles' P written; V-frag shared ---
#pragma unroll
        for (int hf = 0; hf < 2; ++hf) {
#pragma unroll
            for (int c2 = 0; c2 < 2; ++c2) {
                const int c = hf * 2 + c2;
                uint2 wa, wb;
                wa.x = cvt_pk_bf16(sacc[0][c][0], sacc[0][c][1]);
                wa.y = cvt_pk_bf16(sacc[0][c][2], sacc[0][c][3]);
                wb.x = cvt_pk_bf16(sacc[1][c][0], sacc[1][c][1]);
                wb.y = cvt_pk_bf16(sacc[1][c][2], sacc[1][c][3]);
                *(uint2*)&lds[pb0 + ((c2 * 16 + 4 * g) ^ psw)] = wa;
                *(uint2*)&lds[pb1 + ((c2 * 16 + 4 * g) ^ psw)] = wb;
            }
            const bf16x8 pA0 = *(const bf16x8*)&lds[pb0 + ((g * 8) ^ psw)];
            const bf16x8 pA1 = *(const bf16x8*)&lds[pb1 + ((g * 8) ^ psw)];
            __builtin_amdgcn_s_setprio(1);
#pragma unroll
            for (int dt = 0; dt < 4; ++dt) {
                const int vrow = dt * 16 + lc;
                const int swv = (vrow & 7) << 3;
                const bf16x8 vB = *(const bf16x8*)&lds[VO + vrow * 64 + ((hf * 32 + g * 8) ^ swv)];
                oacc[0][dt] = MFMA16(pA0, vB, oacc[0][dt]);
                oacc[1][dt] = MFMA16(pA1, vB, oacc[1][dt]);
            }
            __builtin_amdgcn_s_setprio(0);
        }

        __syncthreads();                 // all reads of tile tt done
        if (tt + 1 < NTH) {
            store_v();                   // regs (prefetched) -> V buffer
            stage_k(tt + 1);             // gl_lds into K buffer
            __syncthreads();             // drains vmcnt + lgkm: tile ready
        }
    }

    // --- final cross-lane l reduction ---
    float ps[2];
#pragma unroll
    for (int s = 0; s < 2; ++s) {
        float p = lsum[s];
        p += __shfl_xor(p, 16);
        p += __shfl_xor(p, 32);
        ps[s] = p;
    }

    // --- 4-way flash-merge (scratch overlays dead K/V: 16384 f32) ---
    if (qq > 0) {
        const int widx = (qq - 1) * 2 + qg;
        const int base = widx * 2048;
#pragma unroll
        for (int s = 0; s < 2; ++s) {
#pragma unroll
            for (int dt = 0; dt < 4; ++dt)
#pragma unroll
                for (int i = 0; i < 4; ++i)
                    ldsf[base + ((s * 4 + dt) * 4 + i) * 64 + lane] = oacc[s][dt][i];
            ldsf[12288 + widx * 256 + s * 64 + lane] = mrun[s];
            ldsf[12288 + widx * 256 + 128 + s * 64 + lane] = ps[s];
        }
    }
    __syncthreads();
    if (qq == 0) {
#pragma unroll
        for (int s = 0; s < 2; ++s) {
            float mj[3], lj[3];
#pragma unroll
            for (int j = 0; j < 3; ++j) {
                const int widx = j * 2 + qg;
                mj[j] = ldsf[12288 + widx * 256 + s * 64 + lane];
                lj[j] = ldsf[12288 + widx * 256 + 128 + s * 64 + lane];
            }
            const float mf = fmaxf(fmaxf(mrun[s], mj[0]), fmaxf(mj[1], mj[2]));
            const float f0 = exp2_fast(mrun[s] - mf);
            float fj[3];
#pragma unroll
            for (int j = 0; j < 3; ++j) fj[j] = exp2_fast(mj[j] - mf);
            const float L = f0 * ps[s] + fj[0] * lj[0] + fj[1] * lj[1] + fj[2] * lj[2];
            const float inv = 1.f / L;
#pragma unroll
            for (int i = 0; i < 4; ++i) {
                const float f0i = __shfl(f0, 4 * g + i, 16);
                const float f1i = __shfl(fj[0], 4 * g + i, 16);
                const float f2i = __shfl(fj[1], 4 * g + i, 16);
                const float f3i = __shfl(fj[2], 4 * g + i, 16);
                const float invi = __shfl(inv, 4 * g + i, 16);
                const int row = q0 + qg * 32 + s * 16 + 4 * g + i;
#pragma unroll
                for (int dt = 0; dt < 4; ++dt) {
                    const int eidx = ((s * 4 + dt) * 4 + i) * 64 + lane;
                    float x = oacc[s][dt][i] * f0i;
                    x += ldsf[(0 * 2 + qg) * 2048 + eidx] * f1i;
                    x += ldsf[(1 * 2 + qg) * 2048 + eidx] * f2i;
                    x += ldsf[(2 * 2 + qg) * 2048 + eidx] * f3i;
                    Oh[(size_t)row * E_DIM + h * D_DIM + dt * 16 + lc] = (_Float16)(x * invi);
                }
            }
        }
    }
}

// ---------------------------------------------------------------------------
extern "C" void kernel_launch(void* const* d_in, const int* in_sizes, int n_in,
                              void* d_out, int out_size, void* d_ws, size_t ws_size,
                              hipStream_t stream)
{
    (void)in_sizes; (void)n_in; (void)out_size; (void)ws_size;

    const float* qkv   = (const float*)d_in[0];
    const float* w_in  = (const float*)d_in[1];
    const float* b_in  = (const float*)d_in[2];
    const float* w_out = (const float*)d_in[3];
    const float* b_out = (const float*)d_in[4];
    float* out = (float*)d_out;

    unsigned char* ws = (unsigned char*)d_ws;
    _Float16* Wt1 = (_Float16*)(ws);                          // 6.29 MB [3072][1024]
    _Float16* Wt2 = (_Float16*)(ws + 6291456);                // 2.10 MB [1024][1024]
    _Float16* Ah1 = (_Float16*)(ws + 8388608);                // 4.19 MB [2048][1024]
    unsigned short* proj = (unsigned short*)(ws + 16777216);  // 12.58 MB bf16 [2048][3072]
    _Float16* Oh = Ah1;   // reuse: Ah1 dead after gemm1

    // 1) fused prep: convert A to f16 + transpose both weights
    prep_kernel<<<3072, 256, 0, stream>>>(qkv, Ah1, w_in, Wt1, w_out, Wt2);

    // 2) proj = qkv @ w_in + b_in (1-pass f16, bf16 out, q-part pre-scaled)
    gemm_f16_kernel<128, 96, 1, 0><<<512, 256, 0, stream>>>(
        Ah1, Ah1, Wt1, b_in, (void*)proj, S_LEN, 3 * E_DIM, E_DIM, 32);

    // 3) flash attention (2-subtile waves, 4 quarters, in-LDS merge) -> Oh f16
    attn_mfma_kernel<<<512, 512, 0, stream>>>(proj, Oh);

    // 4) out = attn @ w_out + b_out (1-pass f16, fp32 out)
    gemm_f16_kernel<64, 64, 0, 0><<<512, 256, 0, stream>>>(
        Oh, Oh, Wt2, b_out, (void*)out, S_LEN, E_DIM, E_DIM, 16);
}

// Round 13
// 89.634 us; speedup vs baseline: 1.3155x; 1.3155x over previous
//
#include <hip/hip_runtime.h>
#include <math.h>

typedef short bf16x8 __attribute__((ext_vector_type(8)));
typedef _Float16 f16x8 __attribute__((ext_vector_type(8)));
typedef _Float16 f16x4 __attribute__((ext_vector_type(4)));
typedef float f32x4 __attribute__((ext_vector_type(4)));
typedef float f32x16 __attribute__((ext_vector_type(16)));
typedef unsigned short u16x4 __attribute__((ext_vector_type(4)));
typedef unsigned short u16x8 __attribute__((ext_vector_type(8)));

#define S_LEN 2048
#define E_DIM 1024
#define H_NUM 16
#define D_DIM 64
#define LDP   (3 * E_DIM)
// softmax scale folded into Q at GEMM1 epilogue: 1/sqrt(64) * log2(e)
#define QSCALE 0.18033688011112042f

#define MFMA16H(a, b, c) __builtin_amdgcn_mfma_f32_16x16x32_f16((a), (b), (c), 0, 0, 0)
#define MFMA32(a, b, c)  __builtin_amdgcn_mfma_f32_32x32x16_bf16((a), (b), (c), 0, 0, 0)

__device__ __forceinline__ unsigned short f2bf(float f) {
    union { float f; unsigned int u; } v; v.f = f;
    unsigned int r = v.u + 0x7FFFu + ((v.u >> 16) & 1u);
    return (unsigned short)(r >> 16);
}
__device__ __forceinline__ float exp2_fast(float x) {
    float r; asm("v_exp_f32 %0, %1" : "=v"(r) : "v"(x)); return r;
}
__device__ __forceinline__ unsigned int cvt_pk_bf16(float lo, float hi) {
    unsigned int r;
    asm("v_cvt_pk_bf16_f32 %0, %1, %2" : "=v"(r) : "v"(lo), "v"(hi));
    return r;
}
// direct global -> LDS, 16B per lane. LDS dest = wave-uniform base + lane*16.
__device__ __forceinline__ void gl_lds16(const void* g, unsigned short* l) {
    __builtin_amdgcn_global_load_lds(
        (const __attribute__((address_space(1))) void*)g,
        (__attribute__((address_space(3))) void*)l, 16, 0, 0);
}

// ---------------------------------------------------------------------------
// Fused prep: [0,2048) convert qkv fp32 -> f16; [2048,2816) transpose w_in;
// [2816,3072) transpose w_out.  (r10-proven)
// ---------------------------------------------------------------------------
__global__ __launch_bounds__(256) void prep_kernel(
    const float* __restrict__ qkv, _Float16* __restrict__ Ah,
    const float* __restrict__ w_in, _Float16* __restrict__ Wt1,
    const float* __restrict__ w_out, _Float16* __restrict__ Wt2)
{
    __shared__ float tile[64][65];
    const int bid = blockIdx.x;
    const int t = threadIdx.x;

    if (bid < 2048) {
        const int i = bid * 256 + t;
        const float4 v = ((const float4*)qkv)[i];
        f16x4 hh;
        hh[0] = (_Float16)v.x; hh[1] = (_Float16)v.y;
        hh[2] = (_Float16)v.z; hh[3] = (_Float16)v.w;
        ((f16x4*)Ah)[i] = hh;
        return;
    }
    const float* B;
    _Float16* Bt;
    int bx, by, N;
    if (bid < 2816) { B = w_in;  Bt = Wt1; N = 3 * E_DIM; bx = (bid - 2048) % 48; by = (bid - 2048) / 48; }
    else            { B = w_out; Bt = Wt2; N = E_DIM;     bx = (bid - 2816) % 16; by = (bid - 2816) / 16; }
    const int K = E_DIM;
    const int k0 = by * 64, n0 = bx * 64;
    const int r4 = t >> 6, c = t & 63;
#pragma unroll
    for (int rep = 0; rep < 16; ++rep)
        tile[rep * 4 + r4][c] = B[(size_t)(k0 + rep * 4 + r4) * N + n0 + c];
    __syncthreads();
#pragma unroll
    for (int rep = 0; rep < 16; ++rep) {
        const int n = rep * 4 + r4;
        Bt[(size_t)(n0 + n) * K + k0 + c] = (_Float16)tile[c][n];
    }
}

// ---------------------------------------------------------------------------
// f16 MFMA GEMM, global_load_lds staging + LDS double buffer (r10-proven).
// ---------------------------------------------------------------------------
template <int BM, int BN, int OUT_MODE, int TWO_PASS>
__global__ __launch_bounds__(256) void gemm_f16_kernel(
    const _Float16* __restrict__ Ah, const _Float16* __restrict__ Al,
    const _Float16* __restrict__ Bt, const float* __restrict__ bias,
    void* __restrict__ Cout, int M, int N, int K, int nbx)
{
    constexpr int AROWS = TWO_PASS ? 2 * BM : BM;
    constexpr int ROWS = AROWS + BN;
    constexpr int NISS = ROWS / 16;
    constexpr int MI = BM / 32, NI = BN / 32;
    __shared__ unsigned short lds[2 * ROWS * 32];

    const int nwg = gridDim.x;
    const int bid = blockIdx.x;
    const int qch = nwg >> 3;
    const int swz = (bid & 7) * qch + (bid >> 3);
    const int n0 = (swz % nbx) * BN;
    const int m0 = (swz / nbx) * BM;

    const int t = threadIdx.x;
    const int wid = t >> 6, lane = t & 63;
    const int wr = wid >> 1, wc = wid & 1;
    const int lc = lane & 15, g = lane >> 4;
    const int lrow = lane >> 2;
    const int lcol = (lane & 3) * 8;

    f32x4 acc[MI][NI];
    const f32x4 zf = {0.f, 0.f, 0.f, 0.f};
#pragma unroll
    for (int mi = 0; mi < MI; ++mi)
#pragma unroll
        for (int ni = 0; ni < NI; ++ni) acc[mi][ni] = zf;

    auto stage = [&](int k0, int b) {
        unsigned short* base = &lds[b * ROWS * 32];
#pragma unroll
        for (int e = wid; e < NISS; e += 4) {
            const int rb = e * 16;
            const int rr = rb + lrow;
            const _Float16* gp;
            if (rb < BM)                            gp = &Ah[(size_t)(m0 + rr) * K + k0 + lcol];
            else if (TWO_PASS && rb < 2 * BM)       gp = &Al[(size_t)(m0 + rr - BM) * K + k0 + lcol];
            else                                    gp = &Bt[(size_t)(n0 + rr - AROWS) * K + k0 + lcol];
            gl_lds16(gp, base + rb * 32);
        }
    };

    stage(0, 0);
    const int NK = K / 32;
    for (int ks = 0; ks < NK; ++ks) {
        __syncthreads();
        if (ks + 1 < NK) stage((ks + 1) * 32, (ks + 1) & 1);
        const unsigned short* cb = &lds[(ks & 1) * ROWS * 32];

        f16x8 bfr[NI];
#pragma unroll
        for (int ni = 0; ni < NI; ++ni)
            bfr[ni] = *(const f16x8*)&cb[(AROWS + wc * (BN / 2) + ni * 16 + lc) * 32 + g * 8];
#pragma unroll
        for (int mi = 0; mi < MI; ++mi) {
            const int ar = wr * (BM / 2) + mi * 16 + lc;
            const f16x8 ah = *(const f16x8*)&cb[ar * 32 + g * 8];
#pragma unroll
            for (int ni = 0; ni < NI; ++ni)
                acc[mi][ni] = MFMA16H(ah, bfr[ni], acc[mi][ni]);
            if (TWO_PASS) {
                const f16x8 al = *(const f16x8*)&cb[(BM + ar) * 32 + g * 8];
#pragma unroll
                for (int ni = 0; ni < NI; ++ni)
                    acc[mi][ni] = MFMA16H(al, bfr[ni], acc[mi][ni]);
            }
        }
    }

#pragma unroll
    for (int ni = 0; ni < NI; ++ni) {
        const int col = n0 + wc * (BN / 2) + ni * 16 + lc;
        const float bv = bias[col];
        float sc = 1.f;
        if (OUT_MODE == 1) sc = (col < E_DIM) ? QSCALE : 1.f;
#pragma unroll
        for (int mi = 0; mi < MI; ++mi) {
            const int rbase = m0 + wr * (BM / 2) + mi * 16 + g * 4;
#pragma unroll
            for (int i = 0; i < 4; ++i) {
                const float v = acc[mi][ni][i] + bv;
                if (OUT_MODE == 1)
                    ((unsigned short*)Cout)[(size_t)(rbase + i) * N + col] = f2bf(v * sc);
                else
                    ((float*)Cout)[(size_t)(rbase + i) * N + col] = v;
            }
        }
    }
}

// ---------------------------------------------------------------------------
// MFMA flash attention, 32x32 MFMA (halves K/V LDS bytes per MAC vs 16x16).
// Block = 64 Q rows x head, 8 waves (512 thr): qg=w&1 (32 q-rows), quarter
// qq=w>>1 (512 kv, 8 tiles of KVB=64). Swapped QK^T: sacc = mfma32(K, Q) ->
// lane owns q-row (lane&31), kv = (reg&3)+8*(reg>>2)+4*(lane>>5) (+32*blk).
// Softmax fully in-lane + one shfl_xor(32). P->PV A-frag assembled in-reg
// via cvt_pk + shfl_xor(32) + select (T12 pattern). K staged via gl_lds with
// pre-swizzled source (r12-proven); V reg-transposed (r12-proven); Q in LDS.
// 4-way in-LDS merge (r12-proven). LDS 72KB -> 2 blocks/CU, grid 512.
// ---------------------------------------------------------------------------
__global__ __launch_bounds__(512, 4) void attn_mfma_kernel(
    const unsigned short* __restrict__ proj, _Float16* __restrict__ Oh)
{
    // elems: K [4 qq][64 kv][64 d] @0 | Vt [4 qq][64 d][64 kv] @16384 | Q @32768
    __shared__ unsigned short lds[36864];   // 72 KB
    float* ldsf = (float*)lds;              // merge scratch overlays dead K/V

    const int t = threadIdx.x;
    const int w = t >> 6, lane = t & 63;
    const int lcol = lane & 31, hi = lane >> 5;
    const int qg = w & 1;        // q-row group (32 rows)
    const int qq = w >> 1;       // kv quarter
    const int ts = t & 127;      // 128-thread quarter staging group

    const int bid = blockIdx.x;
    const int swb = (bid & 7) * 64 + (bid >> 3);
    const int qt = swb & 31;
    const int h  = swb >> 5;
    const int q0 = qt * 64;

    const size_t qoff = (size_t)h * D_DIM;
    const size_t koff = E_DIM + (size_t)h * D_DIM;
    const size_t voff = 2 * E_DIM + (size_t)h * D_DIM;

    const int KO = qq * 4096;
    const int VO = 16384 + qq * 4096;
    const int Q_OFF = 32768;
    const int kvbase = qq * 512;
    const int swl = (lcol & 7) << 3;

    // --- V staging (quarter's 128 threads; reg transpose, r12-proven) ---
    const int kvv = (ts & 15) * 4;       // 4 src kv rows
    const int vd0 = (ts >> 4) * 8;       // 8 dst d rows
    u16x8 vr[4];
    auto load_v = [&](int tile) {
        const int t0 = kvbase + tile * 64;
#pragma unroll
        for (int j = 0; j < 4; ++j)
            vr[j] = *(const u16x8*)&proj[(size_t)(t0 + kvv + j) * LDP + voff + vd0];
    };
    auto store_v = [&]() {
#pragma unroll
        for (int dd = 0; dd < 8; ++dd) {
            const int d = vd0 + dd;
            u16x4 w4;
            w4[0] = vr[0][dd]; w4[1] = vr[1][dd]; w4[2] = vr[2][dd]; w4[3] = vr[3][dd];
            *(u16x4*)&lds[VO + d * 64 + (kvv ^ ((d & 7) << 3))] = w4;
        }
    };

    // --- K staging: gl_lds, pre-swizzled source, linear dest (r12-proven) ---
    const int klr = lane >> 3, ksl = lane & 7;
    const int ksrc = (ksl ^ klr) * 8;
    auto stage_k = [&](int tile) {
        const int t0 = kvbase + tile * 64;
#pragma unroll
        for (int e = 0; e < 4; ++e) {
            const int rb = (qg * 4 + e) * 8;
            gl_lds16(&proj[(size_t)(t0 + rb + klr) * LDP + koff + ksrc],
                     &lds[KO + rb * 64]);
        }
    };

    // --- prologue: stage Q (first 256 thr), V regs->LDS, K gl_lds ---
    if (t < 256) {
        const int r = t >> 2, s = (t & 3) * 16;
        const int sw = (r & 7) << 3;
        const unsigned short* gq = &proj[(size_t)(q0 + r) * LDP + qoff + s];
        const uint4 v0 = ((const uint4*)gq)[0];
        const uint4 v1 = ((const uint4*)gq)[1];
        *(uint4*)&lds[Q_OFF + r * 64 + (s ^ sw)]       = v0;
        *(uint4*)&lds[Q_OFF + r * 64 + ((s + 8) ^ sw)] = v1;
    }
    load_v(0);
    store_v();
    stage_k(0);
    __syncthreads();

    f32x16 oacc[2];
    oacc[0] = 0.f;
    oacc[1] = 0.f;
    float mrun = -1e30f;   // row-uniform high-water mark (T13 defer-max)
    float lsum = 0.f;      // per-lane partial sum

    const int NTH = 8;     // 8 tiles of 64 kv per quarter
    for (int tt = 0; tt < NTH; ++tt) {
        if (tt + 1 < NTH) load_v(tt + 1);   // T14: issue early

        // --- Q fragments (B-operand): lane -> q-col = qg*32+lcol ---
        bf16x8 qf[4];
#pragma unroll
        for (int ks = 0; ks < 4; ++ks)
            qf[ks] = *(const bf16x8*)&lds[Q_OFF + (qg * 32 + lcol) * 64
                                          + ((ks * 16 + hi * 8) ^ swl)];

        // --- QK^T: sacc[b] = S^T block (kv = b*32 + crow, q = lcol) ---
        f32x16 sacc[2];
        sacc[0] = 0.f;
        sacc[1] = 0.f;
        __builtin_amdgcn_s_setprio(1);
#pragma unroll
        for (int b = 0; b < 2; ++b)
#pragma unroll
            for (int ks = 0; ks < 4; ++ks) {
                const bf16x8 kf = *(const bf16x8*)&lds[KO + (b * 32 + lcol) * 64
                                                       + ((ks * 16 + hi * 8) ^ swl)];
                sacc[b] = MFMA32(kf, qf[ks], sacc[b]);
            }
        __builtin_amdgcn_s_setprio(0);

        // --- defer-max (T13): zero cross-lane in common path ---
        float lmax = sacc[0][0];
#pragma unroll
        for (int i = 1; i < 16; ++i) lmax = fmaxf(lmax, sacc[0][i]);
#pragma unroll
        for (int i = 0; i < 16; ++i) lmax = fmaxf(lmax, sacc[1][i]);
        if (__any(lmax > mrun + 8.0f)) {
            const float mx = fmaxf(lmax, __shfl_xor(lmax, 32));
            const float mnew = fmaxf(mrun, mx);
            const float fs = exp2_fast(mrun - mnew);
            lsum *= fs;
            mrun = mnew;
#pragma unroll
            for (int r = 0; r < 16; ++r) {
                const int qr = (r & 3) + 8 * (r >> 2) + 4 * hi;
                const float fr = __shfl(fs, qr);
                oacc[0][r] *= fr;
                oacc[1][r] *= fr;
            }
        }

        // --- exp (base-2, stale max: P <= 2^8) + per-lane partial sum ---
        float psum = 0.f;
#pragma unroll
        for (int b = 0; b < 2; ++b)
#pragma unroll
            for (int i = 0; i < 16; ++i) {
                sacc[b][i] = exp2_fast(sacc[b][i] - mrun);
                psum += sacc[b][i];
            }
        lsum += psum;

        // --- P -> A-frag in registers (cvt_pk + shfl_xor(32) + select), PV ---
#pragma unroll
        for (int b = 0; b < 2; ++b) {
            unsigned int pk0[4], pk1[4], sw0[4], sw1[4];
#pragma unroll
            for (int G = 0; G < 4; ++G) {
                pk0[G] = cvt_pk_bf16(sacc[b][4 * G + 0], sacc[b][4 * G + 1]);
                pk1[G] = cvt_pk_bf16(sacc[b][4 * G + 2], sacc[b][4 * G + 3]);
            }
#pragma unroll
            for (int G = 0; G < 4; ++G) {
                sw0[G] = (unsigned int)__shfl_xor((int)pk0[G], 32);
                sw1[G] = (unsigned int)__shfl_xor((int)pk1[G], 32);
            }
            __builtin_amdgcn_s_setprio(1);
#pragma unroll
            for (int ksp = 0; ksp < 2; ++ksp) {
                const int Ge = 2 * ksp, Go = 2 * ksp + 1;
                uint4 au;
                au.x = hi ? sw0[Go] : pk0[Ge];
                au.y = hi ? sw1[Go] : pk1[Ge];
                au.z = hi ? pk0[Go] : sw0[Ge];
                au.w = hi ? pk1[Go] : sw1[Ge];
                const bf16x8 pa = *(const bf16x8*)&au;
                const int vcol = b * 32 + ksp * 16 + hi * 8;
#pragma unroll
                for (int dt = 0; dt < 2; ++dt) {
                    const bf16x8 vf = *(const bf16x8*)&lds[VO + (dt * 32 + lcol) * 64
                                                           + (vcol ^ swl)];
                    oacc[dt] = MFMA32(pa, vf, oacc[dt]);
                }
            }
            __builtin_amdgcn_s_setprio(0);
        }

        __syncthreads();                 // all reads of tile tt done
        if (tt + 1 < NTH) {
            store_v();                   // prefetched regs -> V buffer
            stage_k(tt + 1);             // gl_lds -> K buffer
            __syncthreads();             // drains vmcnt+lgkm: tile ready
        }
    }

    // --- final row-sum (row = lanes l, l^32) ---
    const float ps = lsum + __shfl_xor(lsum, 32);

    // --- 4-way flash-merge (scratch overlays dead K/V) ---
    if (qq > 0) {
        const int widx = (qq - 1) * 2 + qg;
        const int base = widx * 2048;
#pragma unroll
        for (int dt = 0; dt < 2; ++dt)
#pragma unroll
            for (int r = 0; r < 16; ++r)
                ldsf[base + (dt * 16 + r) * 64 + lane] = oacc[dt][r];
        ldsf[12288 + widx * 128 + lane] = mrun;
        ldsf[12288 + widx * 128 + 64 + lane] = ps;
    }
    __syncthreads();
    if (qq == 0) {
        float mj[3], lj[3];
#pragma unroll
        for (int j = 0; j < 3; ++j) {
            const int widx = j * 2 + qg;
            mj[j] = ldsf[12288 + widx * 128 + lane];
            lj[j] = ldsf[12288 + widx * 128 + 64 + lane];
        }
        const float mf = fmaxf(fmaxf(mrun, mj[0]), fmaxf(mj[1], mj[2]));
        const float f0 = exp2_fast(mrun - mf);
        float fj[3];
#pragma unroll
        for (int j = 0; j < 3; ++j) fj[j] = exp2_fast(mj[j] - mf);
        const float L = f0 * ps + fj[0] * lj[0] + fj[1] * lj[1] + fj[2] * lj[2];
        const float inv = 1.f / L;
#pragma unroll
        for (int r = 0; r < 16; ++r) {
            const int qr = (r & 3) + 8 * (r >> 2) + 4 * hi;
            const float f0r = __shfl(f0, qr);
            const float f1r = __shfl(fj[0], qr);
            const float f2r = __shfl(fj[1], qr);
            const float f3r = __shfl(fj[2], qr);
            const float invr = __shfl(inv, qr);
            const int row = q0 + qg * 32 + qr;
#pragma unroll
            for (int dt = 0; dt < 2; ++dt) {
                const int eidx = (dt * 16 + r) * 64 + lane;
                float x = oacc[dt][r] * f0r;
                x += ldsf[(0 + qg) * 2048 + eidx] * f1r;
                x += ldsf[(2 + qg) * 2048 + eidx] * f2r;
                x += ldsf[(4 + qg) * 2048 + eidx] * f3r;
                Oh[(size_t)row * E_DIM + h * D_DIM + dt * 32 + lcol]
                    = (_Float16)(x * invr);
            }
        }
    }
}

// ---------------------------------------------------------------------------
extern "C" void kernel_launch(void* const* d_in, const int* in_sizes, int n_in,
                              void* d_out, int out_size, void* d_ws, size_t ws_size,
                              hipStream_t stream)
{
    (void)in_sizes; (void)n_in; (void)out_size; (void)ws_size;

    const float* qkv   = (const float*)d_in[0];
    const float* w_in  = (const float*)d_in[1];
    const float* b_in  = (const float*)d_in[2];
    const float* w_out = (const float*)d_in[3];
    const float* b_out = (const float*)d_in[4];
    float* out = (float*)d_out;

    unsigned char* ws = (unsigned char*)d_ws;
    _Float16* Wt1 = (_Float16*)(ws);                          // 6.29 MB [3072][1024]
    _Float16* Wt2 = (_Float16*)(ws + 6291456);                // 2.10 MB [1024][1024]
    _Float16* Ah1 = (_Float16*)(ws + 8388608);                // 4.19 MB [2048][1024]
    unsigned short* proj = (unsigned short*)(ws + 16777216);  // 12.58 MB bf16 [2048][3072]
    _Float16* Oh = Ah1;   // reuse: Ah1 dead after gemm1

    // 1) fused prep: convert A to f16 + transpose both weights
    prep_kernel<<<3072, 256, 0, stream>>>(qkv, Ah1, w_in, Wt1, w_out, Wt2);

    // 2) proj = qkv @ w_in + b_in (1-pass f16, bf16 out, q-part pre-scaled)
    gemm_f16_kernel<128, 96, 1, 0><<<512, 256, 0, stream>>>(
        Ah1, Ah1, Wt1, b_in, (void*)proj, S_LEN, 3 * E_DIM, E_DIM, 32);

    // 3) flash attention (32x32 MFMA, 4 kv-quarters, in-LDS merge) -> Oh f16
    attn_mfma_kernel<<<512, 512, 0, stream>>>(proj, Oh);

    // 4) out = attn @ w_out + b_out (1-pass f16, fp32 out)
    gemm_f16_kernel<64, 64, 0, 0><<<512, 256, 0, stream>>>(
        Oh, Oh, Wt2, b_out, (void*)out, S_LEN, E_DIM, E_DIM, 16);
}